// Round 6
// baseline (252.701 us; speedup 1.0000x reference)
//
#include <hip/hip_runtime.h>

// RoIMaskAlignAvg: features (B=2, C=256, H=200, W=272) fp32, rois (N=256,5)
// -> out (N, C, 14, 14) fp32.
//
// v6 = v5 (software-pipelined span staging) + the MISSING ds_read/DMA
// ordering guard that v4 had and v5 dropped (the v5 correctness bug):
//   s_waitcnt lgkmcnt(0) BEFORE each stage() -- guarantees the wave's
//   prior-iteration ds_reads of the target buffer have EXECUTED before the
//   overwriting global_load_lds is issued. Without it, under LDS-unit
//   backlog (~16 waves x 8 ds_reads/iter share the pipe), a queued ds_read
//   can read the buffer AFTER the next row's DMA lands (~200cy after its
//   issue) -> wrong-row data (v5: absmax 0.89).
// The expensive latency stays hidden: vmcnt(4) waits only for row i's 4
// loads while row i+1's 4 remain in flight under geometry+FMA (counted
// vmcnt, never 0 in the loop).
//  - Uniform 4 global_load_lds per iteration (rows yl,yh x pairs A,B),
//    double-buffered; span-masked (ldact) so L1 work ~44% of full window.
//  - Bank-conflict fix: half1's window starts 8 cols lower (s0c1) ->
//    LDS banks shifted by 8 vs half0. Coverage: span<=101, +8 shift <=109
//    <=127 slots; clamp cases verified in-line below.
//  - Row buffers zero-initialized once (never-staged slots read as 0.0,
//    consumed only with weight 0; residue could be NaN and 0*NaN!=0).
//  - Outputs in registers (static idx, full unroll); after final vmcnt(0)
//    drain they overlay the dead row buffers and write back coalesced.
// Kept: XCD swizzle (1.74MB/XCD L2 slice), CPB=4, wave-uniform y-geometry,
// register shuffle pooling. LDS = 16.4 KB/block.
//
// Wave LDS layout (floats): buf b in [b*1024, b*1024+1024):
//   +0 A-LO, +256 B-LO, +512 A-HI, +768 B-HI (each: half h at h*128+col)
//   [2048,2056) pad; out staging overlays [0,392) after the loop.

#define AH_  14
#define AW_  14
#define C_   256
#define H_   200
#define W_   272
#define HW_  (H_ * W_)
#define CPB  4
#define WBUF 2056

#define GLOAD_LDS16(g, l)                                                     \
  __builtin_amdgcn_global_load_lds(                                           \
      (const __attribute__((address_space(1))) void*)(g),                     \
      (__attribute__((address_space(3))) void*)(l), 16, 0, 0)

__global__ __launch_bounds__(128)
void roi_mask_align_avg_kernel(const float* __restrict__ feat,
                               const float* __restrict__ rois,
                               float* __restrict__ out) {
    __shared__ float Ls[2][WBUF];   // 16448 B/block

    // --- XCD-aware swizzle (identical to v0..v4) ---
    const int p   = blockIdx.x;
    const int xcd = p & 7;
    const int q   = p >> 3;
    const int n   = q & 255;           // roi index (advances fastest)
    const int cgi = q >> 8;            // 0..7
    const int cg  = cgi * 8 + xcd;     // 0..63
    const int c0  = cg * CPB;

    const int tid  = threadIdx.x;
    const int wave = tid >> 6;
    const int lane = tid & 63;
    const int half = lane >> 5;        // channel within a pair
    const int ix   = lane & 31;        // sample-x index (0..29 used)

    float* __restrict__ LsW = Ls[wave];
    // zero-init row buffers (never-staged slots must read 0.0, not residue)
    {
        float4* L4 = (float4*)LsW;
        for (int o = lane; o < WBUF / 4; o += 64)
            L4[o] = make_float4(0.f, 0.f, 0.f, 0.f);
    }
    asm volatile("s_waitcnt lgkmcnt(0)" ::: "memory");

    // --- per-roi geometry (block-uniform; fp op order preserved) ---
    const float r0f = rois[n * 5 + 0];
    const float x1s = rois[n * 5 + 1] * 0.25f;
    const float y1s = rois[n * 5 + 2] * 0.25f;
    const float x2s = rois[n * 5 + 3] * 0.25f;
    const float y2s = rois[n * 5 + 4] * 0.25f;
    const int   b   = (int)r0f;

    const float cx = 0.5f * (x1s + x2s), cy = 0.5f * (y1s + y2s);
    const float hw = 0.5f * (x2s - x1s), hh = 0.5f * (y2s - y1s);
    const float x1 = cx - hw, x2 = cx + hw;
    const float y1 = cy - hh, y2 = cy + hh;
    const float roi_w = fmaxf(x2 - x1, 1.0f);
    const float roi_h = fmaxf(y2 - y1, 1.0f);
    const float sub_w = roi_w * (1.0f / 15.0f) * 0.5f;
    const float sub_h = roi_h * (1.0f / 15.0f) * 0.5f;

    // --- x-direction sample metadata: per lane, computed once ---
    const float sx  = x1 + ((float)ix + 0.5f) * sub_w;
    const bool  vx_ = (sx > -1.0f) && (sx < (float)W_) && (ix < 30);
    const float ccx = fminf(fmaxf(sx, 0.0f), (float)(W_ - 1));
    const float lox = floorf(ccx);
    const int   xl  = (int)lox;
    const int   xh  = min(xl + 1, W_ - 1);
    const float fx  = ccx - lox;
    const float vmx = vx_ ? 1.0f : 0.0f;
    const float wx0 = (1.0f - fx) * vmx;
    const float wx1 = fx * vmx;

    // --- per-half span windows (half1 shifted -8 cols => bank shift 8) ---
    // Coverage: span = xh29-s0 <= 101 (roi_w<=103.2 -> 29*sub_w<=99.8).
    //  half0: window [s0c0, s0c0+128), s0c0=min(s0,144): covers to 271 when
    //         clamped, else s0+127.
    //  half1: s0c1=clamp(s0-8,0,144): slack 101+8=109<=127; for 144<s0<152,
    //         top = s0c1+127 = s0+119 >= s0+101 ✓.
    const int s0    = __builtin_amdgcn_readfirstlane(xl);   // xl at ix=0
    const int s0c0  = min(s0, W_ - 128);
    const int s0c1  = max(min(s0 - 8, W_ - 128), 0);
    const int s0ch  = half ? s0c1 : s0c0;
    const int xh29  = __builtin_amdgcn_readlane(xh, 29);    // max needed col
    const int spanh = xh29 - s0ch;                          // per-half span
    const bool ldact = (ix * 4) <= spanh;                   // staging mask
    const int iA    = half * 128 + (xl - s0ch);             // loop-invariant

    const float* __restrict__ bpA = feat + ((size_t)b * C_ + c0) * (size_t)HW_;
    const float* __restrict__ gAl = bpA + (size_t)half * HW_ + s0ch + 4 * ix;
    const float* __restrict__ gBl = gAl + 2 * HW_;

    const int  aw   = ix >> 1;
    const bool emit = ((lane & 1) == 0) && (aw < AW_);
    const int  iy0  = wave * 14;       // wave0: iy 0..15, wave1: iy 14..29

    // wave-uniform y geometry for one sample row
    auto geom = [&](int iy, int& olo, int& ohi, float& wy0, float& wy1) {
        const float sy  = y1 + ((float)iy + 0.5f) * sub_h;
        const bool  vy_ = (sy > -1.0f) && (sy < (float)H_);
        const float ccy = fminf(fmaxf(sy, 0.0f), (float)(H_ - 1));
        const float loy = floorf(ccy);
        const float fy  = ccy - loy;
        const float vmy = vy_ ? 1.0f : 0.0f;
        wy0 = (1.0f - fy) * vmy;
        wy1 = fy * vmy;
        const int yl_s = __builtin_amdgcn_readfirstlane((int)loy);
        const int yh_s = min(yl_s + 1, H_ - 1);
        olo = yl_s * W_;
        ohi = yh_s * W_;
    };
    auto stage = [&](int bb, int olo, int ohi) {
        float* d = LsW + bb * 1024;
        if (ldact) {
            GLOAD_LDS16(gAl + olo, d);
            GLOAD_LDS16(gBl + olo, d + 256);
            GLOAD_LDS16(gAl + ohi, d + 512);
            GLOAD_LDS16(gBl + ohi, d + 768);
        }
    };

    // --- prologue: stage row iy0 into buf0 ---
    int   olo_c, ohi_c;  float wy0_c, wy1_c;
    geom(iy0, olo_c, ohi_c, wy0_c, wy1_c);
    stage(0, olo_c, ohi_c);

    float outA[7], outB[7];
    float prevSA = 0.f, prevSB = 0.f, PA = 0.f, PB = 0.f;

    #pragma unroll
    for (int i = 0; i < 16; ++i) {
        // next row's geometry (VALU only)
        int olo_n, ohi_n; float wy0_n, wy1_n;
        geom(iy0 + i + 1, olo_n, ohi_n, wy0_n, wy1_n);

        // ORDERING GUARD (the v5 bug): prior iteration's ds_reads of the
        // target buffer must have executed before the overwriting DMA
        // is issued. Cheap (LDS-pipe only); vmem latency stays pipelined.
        asm volatile("s_waitcnt lgkmcnt(0)" ::: "memory");

        // issue next row's stage (dangling at i=15: valid rows, never read)
        stage((i + 1) & 1, olo_n, ohi_n);

        // wait only for row i's 4 loads; row i+1's 4 remain in flight
        asm volatile("s_waitcnt vmcnt(4)" ::: "memory");

        const float* d = LsW + (i & 1) * 1024;
        const float alo0 = d[iA],       alo1 = d[iA + 1];
        const float blo0 = d[256 + iA], blo1 = d[256 + iA + 1];
        const float ahi0 = d[512 + iA], ahi1 = d[512 + iA + 1];
        const float bhi0 = d[768 + iA], bhi1 = d[768 + iA + 1];

        const float w00 = wy0_c * wx0, w01 = wy0_c * wx1;
        const float w10 = wy1_c * wx0, w11 = wy1_c * wx1;
        PA += alo0 * w00 + alo1 * w01 + ahi0 * w10 + ahi1 * w11;
        PB += blo0 * w00 + blo1 * w01 + bhi0 * w10 + bhi1 * w11;

        if (i & 1) {
            const float tA = PA + __shfl_xor(PA, 1, 64);
            const float uA = tA + __shfl_down(tA, 2, 64);
            const float tB = PB + __shfl_xor(PB, 1, 64);
            const float uB = tB + __shfl_down(tB, 2, 64);
            const int kk = i >> 1;
            if (kk > 0) {
                outA[kk - 1] = (prevSA + uA) * 0.0625f;
                outB[kk - 1] = (prevSB + uB) * 0.0625f;
            }
            prevSA = uA; prevSB = uB;
            PA = 0.f; PB = 0.f;
        }
        olo_c = olo_n; ohi_c = ohi_n; wy0_c = wy0_n; wy1_c = wy1_n;
    }

    // --- drain dangling loads, then overlay out staging on row buffers ---
    asm volatile("s_waitcnt vmcnt(0)" ::: "memory");
    if (emit) {
        #pragma unroll
        for (int k = 0; k < 7; ++k) {
            LsW[half * 98 + k * AW_ + aw]       = outA[k];
            LsW[(2 + half) * 98 + k * AW_ + aw] = outB[k];
        }
    }

    // --- coalesced writeback: wave w writes rows [7w,7w+7) of 4 channels ---
    float* __restrict__ op = out + ((size_t)n * C_ + c0) * (AH_ * AW_);
    for (int o = lane; o < CPB * 7 * AW_; o += 64) {   // 392 floats
        const int ch  = o / 98;
        const int rem = o - ch * 98;
        op[ch * (AH_ * AW_) + wave * 98 + rem] = LsW[o];
    }
}

extern "C" void kernel_launch(void* const* d_in, const int* in_sizes, int n_in,
                              void* d_out, int out_size, void* d_ws, size_t ws_size,
                              hipStream_t stream) {
    const float* feat = (const float*)d_in[0];
    const float* rois = (const float*)d_in[1];
    float* out = (float*)d_out;
    const int grid = 256 * (C_ / CPB);   // 16384 blocks, 128 threads
    roi_mask_align_avg_kernel<<<grid, 128, 0, stream>>>(feat, rois, out);
}

// Round 7
// 245.219 us; speedup vs baseline: 1.0305x; 1.0305x over previous
//
#include <hip/hip_runtime.h>

// RoIMaskAlignAvg: features (B=2, C=256, H=200, W=272) fp32, rois (N=256,5)
// -> out (N, C, 14, 14) fp32.
//
// v7 = v4's proven serial event staging (108us anchor) + LANE-PARALLEL
// GEOMETRY -> SGPR SCHEDULE + minimal LDS:
//  - lanes 0..15 each compute ONE sample row's y-geometry (yl,yh,wy0,wy1,
//    olo,ohi) and its reuse case vs the previous row (shfl_up):
//    0=full reuse, 1=shift (new lo := old hi regs, stage hi), 2=stage both.
//    The 16-iter unrolled main loop pulls per-row values via v_readlane
//    (uniform) -> scalar branches, scalar row offsets, SGPR weights.
//    Replaces ~45 VALU/row of serial geometry+readfirstlane with ~18.
//  - Single 4KB row buffer per wave (no double buffer: events are serial
//    with vmcnt(0), v4-style). Outputs live in registers (static unroll)
//    and overlay the dead buffer for coalesced writeback. LDS=8.2KB/block
//    -> occupancy cap 16 blocks/CU = 100% (v6's 16.5KB gave 44% occ).
//  - No zero-init: every read col <= spanh is staged by construction;
//    invalid lanes (ix>=30, weight 0) read clamped index 0 (always staged,
//    finite). v4's NaN-residue hazard closed without the init pass.
//  - No per-half window shift (v6 showed it didn't reduce conflicts);
//    both halves share window start s0c; halves sit +512B apart = 2
//    lanes/bank = free on CDNA4.
//  - lgkm guard before each stage (the v5 race fix) + vmcnt(0) before
//    reads (v4-proven ordering).
// Kept: XCD swizzle (1.74MB/XCD L2-resident channel slice), CPB=4,
// register shuffle pooling, coalesced writeback.
//
// Wave LDS layout (floats, 1024): A-LO@0, B-LO@256, A-HI@512, B-HI@768
// (each 256: half h at h*128 + (col-s0c)); out staging overlays [0,392).

#define AH_  14
#define AW_  14
#define C_   256
#define H_   200
#define W_   272
#define HW_  (H_ * W_)
#define CPB  4

#define GLOAD_LDS16(g, l)                                                     \
  __builtin_amdgcn_global_load_lds(                                           \
      (const __attribute__((address_space(1))) void*)(g),                     \
      (__attribute__((address_space(3))) void*)(l), 16, 0, 0)

__global__ __launch_bounds__(128, 8)
void roi_mask_align_avg_kernel(const float* __restrict__ feat,
                               const float* __restrict__ rois,
                               float* __restrict__ out) {
    __shared__ float Ls[2][1024];   // 8192 B/block

    // --- XCD-aware swizzle (identical to v0..v6) ---
    const int p   = blockIdx.x;
    const int xcd = p & 7;
    const int q   = p >> 3;
    const int n   = q & 255;           // roi index (advances fastest)
    const int cgi = q >> 8;            // 0..7
    const int cg  = cgi * 8 + xcd;     // 0..63
    const int c0  = cg * CPB;

    const int tid  = threadIdx.x;
    const int wave = tid >> 6;
    const int lane = tid & 63;
    const int half = lane >> 5;        // channel within a pair
    const int ix   = lane & 31;        // sample-x index (0..29 used)

    float* __restrict__ LsW = Ls[wave];

    // --- per-roi geometry (block-uniform; fp op order preserved) ---
    const float r0f = rois[n * 5 + 0];
    const float x1s = rois[n * 5 + 1] * 0.25f;
    const float y1s = rois[n * 5 + 2] * 0.25f;
    const float x2s = rois[n * 5 + 3] * 0.25f;
    const float y2s = rois[n * 5 + 4] * 0.25f;
    const int   b   = (int)r0f;

    const float cx = 0.5f * (x1s + x2s), cy = 0.5f * (y1s + y2s);
    const float hw = 0.5f * (x2s - x1s), hh = 0.5f * (y2s - y1s);
    const float x1 = cx - hw, x2 = cx + hw;
    const float y1 = cy - hh, y2 = cy + hh;
    const float roi_w = fmaxf(x2 - x1, 1.0f);
    const float roi_h = fmaxf(y2 - y1, 1.0f);
    const float sub_w = roi_w * (1.0f / 15.0f) * 0.5f;
    const float sub_h = roi_h * (1.0f / 15.0f) * 0.5f;

    // --- x-direction sample metadata: per lane, computed once ---
    const float sx  = x1 + ((float)ix + 0.5f) * sub_w;
    const bool  vx_ = (sx > -1.0f) && (sx < (float)W_) && (ix < 30);
    const float ccx = fminf(fmaxf(sx, 0.0f), (float)(W_ - 1));
    const float lox = floorf(ccx);
    const int   xl  = (int)lox;
    const int   xh  = min(xl + 1, W_ - 1);
    const float fx  = ccx - lox;
    const float vmx = vx_ ? 1.0f : 0.0f;
    const float wx0 = (1.0f - fx) * vmx;
    const float wx1 = fx * vmx;

    // --- span window (shared by both halves; span <= 122 < 128 proven) ---
    const int s0    = __builtin_amdgcn_readfirstlane(xl);   // xl at ix=0
    const int s0c   = min(s0, W_ - 128);
    const int xh29  = __builtin_amdgcn_readlane(xh, 29);    // max needed col
    const int spanh = xh29 - s0c;
    const bool ldact = (ix * 4) <= spanh;                   // staging mask
    // invalid lanes (weight 0) read slot 0: always staged, always finite
    const int iA    = half * 128 + (vx_ ? (xl - s0c) : 0);

    const float* __restrict__ bpA = feat + ((size_t)b * C_ + c0) * (size_t)HW_;
    const float* __restrict__ gAl = bpA + (size_t)half * HW_ + s0c + 4 * ix;
    const float* __restrict__ gBl = gAl + 2 * HW_;

    const int  aw   = ix >> 1;
    const bool emit = ((lane & 1) == 0) && (aw < AW_);
    const int  iy0  = wave * 14;       // wave0: iy 0..15, wave1: iy 14..29

    // --- LANE-PARALLEL y-geometry: lane (lane&15) computes row iy0+l ---
    const int   l    = lane & 15;
    const float syl  = y1 + ((float)(iy0 + l) + 0.5f) * sub_h;
    const bool  vyl  = (syl > -1.0f) && (syl < (float)H_);
    const float ccyl = fminf(fmaxf(syl, 0.0f), (float)(H_ - 1));
    const float loyl = floorf(ccyl);
    const float fyl  = ccyl - loyl;
    const float vmyl = vyl ? 1.0f : 0.0f;
    const int   yll  = (int)loyl;
    const int   yhl  = min(yll + 1, H_ - 1);
    const int   wy0b = __float_as_int((1.0f - fyl) * vmyl);
    const int   wy1b = __float_as_int(fyl * vmyl);
    const int   olol = yll * W_;
    const int   ohil = yhl * W_;
    const int   pyll = __shfl_up(yll, 1, 64);   // prev row's yl (junk at l=0)
    const int   pyhl = __shfl_up(yhl, 1, 64);
    // case: 0 = reuse both rows, 1 = shift (yl == prev yh), 2 = stage both
    const int   casel = (l == 0) ? 2
                       : (yll == pyll) ? 0
                       : (yll == pyhl) ? 1 : 2;

    // --- main loop: schedule pulled from lanes via readlane (uniform) ---
    float alo0 = 0.f, alo1 = 0.f, ahi0 = 0.f, ahi1 = 0.f;
    float blo0 = 0.f, blo1 = 0.f, bhi0 = 0.f, bhi1 = 0.f;
    float outA[7], outB[7];
    float prevSA = 0.f, prevSB = 0.f, PA = 0.f, PB = 0.f;

    #pragma unroll
    for (int i = 0; i < 16; ++i) {
        const int   sc  = __builtin_amdgcn_readlane(casel, i);
        const float wy0 = __int_as_float(__builtin_amdgcn_readlane(wy0b, i));
        const float wy1 = __int_as_float(__builtin_amdgcn_readlane(wy1b, i));

        if (sc == 1) {
            // shift: prev hi row -> lo (registers); stage only the new hi
            alo0 = ahi0; alo1 = ahi1; blo0 = bhi0; blo1 = bhi1;
            const int ohi = __builtin_amdgcn_readlane(ohil, i);
            // guard: prior ds_reads of this buffer must have executed
            // before the overwriting DMA is issued (v5 race fix)
            asm volatile("s_waitcnt lgkmcnt(0)" ::: "memory");
            if (ldact) {
                GLOAD_LDS16(gAl + ohi, LsW + 512);
                GLOAD_LDS16(gBl + ohi, LsW + 768);
            }
            asm volatile("s_waitcnt vmcnt(0)" ::: "memory");
            ahi0 = LsW[512 + iA]; ahi1 = LsW[512 + iA + 1];
            bhi0 = LsW[768 + iA]; bhi1 = LsW[768 + iA + 1];
        } else if (sc == 2) {
            const int olo = __builtin_amdgcn_readlane(olol, i);
            const int ohi = __builtin_amdgcn_readlane(ohil, i);
            asm volatile("s_waitcnt lgkmcnt(0)" ::: "memory");
            if (ldact) {
                GLOAD_LDS16(gAl + olo, LsW);
                GLOAD_LDS16(gBl + olo, LsW + 256);
                GLOAD_LDS16(gAl + ohi, LsW + 512);
                GLOAD_LDS16(gBl + ohi, LsW + 768);
            }
            asm volatile("s_waitcnt vmcnt(0)" ::: "memory");
            alo0 = LsW[iA];       alo1 = LsW[iA + 1];
            blo0 = LsW[256 + iA]; blo1 = LsW[256 + iA + 1];
            ahi0 = LsW[512 + iA]; ahi1 = LsW[512 + iA + 1];
            bhi0 = LsW[768 + iA]; bhi1 = LsW[768 + iA + 1];
        }
        // (sc == 0: full reuse, registers already hold both rows)

        const float w00 = wy0 * wx0, w01 = wy0 * wx1;
        const float w10 = wy1 * wx0, w11 = wy1 * wx1;
        PA += alo0 * w00 + alo1 * w01 + ahi0 * w10 + ahi1 * w11;
        PB += blo0 * w00 + blo1 * w01 + bhi0 * w10 + bhi1 * w11;

        if (i & 1) {
            const float tA = PA + __shfl_xor(PA, 1, 64);
            const float uA = tA + __shfl_down(tA, 2, 64);
            const float tB = PB + __shfl_xor(PB, 1, 64);
            const float uB = tB + __shfl_down(tB, 2, 64);
            const int kk = i >> 1;
            if (kk > 0) {
                outA[kk - 1] = (prevSA + uA) * 0.0625f;
                outB[kk - 1] = (prevSB + uB) * 0.0625f;
            }
            prevSA = uA; prevSB = uB;
            PA = 0.f; PB = 0.f;
        }
    }

    // --- overlay out staging on the (dead) row buffer, write coalesced ---
    if (emit) {
        #pragma unroll
        for (int k = 0; k < 7; ++k) {
            LsW[half * 98 + k * AW_ + aw]       = outA[k];
            LsW[(2 + half) * 98 + k * AW_ + aw] = outB[k];
        }
    }
    float* __restrict__ op = out + ((size_t)n * C_ + c0) * (AH_ * AW_);
    for (int o = lane; o < CPB * 7 * AW_; o += 64) {   // 392 floats
        const int ch  = o / 98;
        const int rem = o - ch * 98;
        op[ch * (AH_ * AW_) + wave * 98 + rem] = LsW[o];
    }
}

extern "C" void kernel_launch(void* const* d_in, const int* in_sizes, int n_in,
                              void* d_out, int out_size, void* d_ws, size_t ws_size,
                              hipStream_t stream) {
    const float* feat = (const float*)d_in[0];
    const float* rois = (const float*)d_in[1];
    float* out = (float*)d_out;
    const int grid = 256 * (C_ / CPB);   // 16384 blocks, 128 threads
    roi_mask_align_avg_kernel<<<grid, 128, 0, stream>>>(feat, rois, out);
}

// Round 8
// 227.774 us; speedup vs baseline: 1.1094x; 1.0766x over previous
//
#include <hip/hip_runtime.h>

// RoIMaskAlignAvg: features (B=2, C=256, H=200, W=272) fp32, rois (N=256,5)
// -> out (N, C, 14, 14) fp32.
//
// v8 = v4's case-dependent staging schedule (FETCH floor 46MB)
//    + v7's lane-parallel geometry -> SGPR schedule (short event chain)
//    + depth-1 EVENT PIPELINE with counted vmcnt (v6's idea, minus its two
//      failure causes: uniform-4 loads and occupancy collapse):
//   at row i, issue row i+1's loads (0/2/4 by its scalar case) into the
//   other 4KB buffer, then s_waitcnt vmcnt(n_next) -- waits only for row
//   i's loads; row i+1's stay in flight under row i's ds_read+FMA+pooling.
//   vmcnt immediates live inside the uniform case branches.
//  - lgkm guard before each DMA issue (v5 race fix, v6-proven).
//  - Lane-parallel y-geometry: lanes 0..15 compute one row each (yl,yh,
//    weights, offsets, reuse-case via shfl_up); main loop pulls via
//    v_readlane at constant index -> scalar branches, SGPR weights.
//  - Occupancy DELIBERATELY pinned at v4's L2-stable regime (v7 lesson:
//    occupancy ^ -> per-XCD L2 window ^ -> FETCH/WRITE blow up):
//    LDS 16.4KB/block -> 10 blocks/CU = 62.5%; launch_bounds(128), no min.
//  - No zero-init: invalid lanes (weight 0) read slot 0/128 of the active
//    buffer, which every staged event writes (finite); all valid reads
//    (xl,xh <= xh29) are covered by the ldact span mask.
//  - Outputs in registers; after final vmcnt(0) they overlay the dead row
//    buffer and write back coalesced.
// Kept: XCD swizzle (1.74MB/XCD slice), CPB=4, register shuffle pooling.
//
// Wave LDS (floats): buf p at [p*1024, p*1024+1024):
//   +0 A-LO, +256 B-LO, +512 A-HI, +768 B-HI (half h at h*128 + (col-s0c));
// out staging overlays buf0 [0,392) after the loop.

#define AH_  14
#define AW_  14
#define C_   256
#define H_   200
#define W_   272
#define HW_  (H_ * W_)
#define CPB  4

#define GLOAD_LDS16(g, l)                                                     \
  __builtin_amdgcn_global_load_lds(                                           \
      (const __attribute__((address_space(1))) void*)(g),                     \
      (__attribute__((address_space(3))) void*)(l), 16, 0, 0)

__global__ __launch_bounds__(128)
void roi_mask_align_avg_kernel(const float* __restrict__ feat,
                               const float* __restrict__ rois,
                               float* __restrict__ out) {
    __shared__ float Ls[2][2048];   // 16384 B/block -> 10 blocks/CU

    // --- XCD-aware swizzle (identical to v0..v7) ---
    const int p   = blockIdx.x;
    const int xcd = p & 7;
    const int q   = p >> 3;
    const int n   = q & 255;           // roi index (advances fastest)
    const int cgi = q >> 8;            // 0..7
    const int cg  = cgi * 8 + xcd;     // 0..63
    const int c0  = cg * CPB;

    const int tid  = threadIdx.x;
    const int wave = tid >> 6;
    const int lane = tid & 63;
    const int half = lane >> 5;        // channel within a pair
    const int ix   = lane & 31;        // sample-x index (0..29 used)

    float* __restrict__ LsW = Ls[wave];

    // --- per-roi geometry (block-uniform; fp op order preserved) ---
    const float r0f = rois[n * 5 + 0];
    const float x1s = rois[n * 5 + 1] * 0.25f;
    const float y1s = rois[n * 5 + 2] * 0.25f;
    const float x2s = rois[n * 5 + 3] * 0.25f;
    const float y2s = rois[n * 5 + 4] * 0.25f;
    const int   b   = (int)r0f;

    const float cx = 0.5f * (x1s + x2s), cy = 0.5f * (y1s + y2s);
    const float hw = 0.5f * (x2s - x1s), hh = 0.5f * (y2s - y1s);
    const float x1 = cx - hw, x2 = cx + hw;
    const float y1 = cy - hh, y2 = cy + hh;
    const float roi_w = fmaxf(x2 - x1, 1.0f);
    const float roi_h = fmaxf(y2 - y1, 1.0f);
    const float sub_w = roi_w * (1.0f / 15.0f) * 0.5f;
    const float sub_h = roi_h * (1.0f / 15.0f) * 0.5f;

    // --- x-direction sample metadata: per lane, computed once ---
    const float sx  = x1 + ((float)ix + 0.5f) * sub_w;
    const bool  vx_ = (sx > -1.0f) && (sx < (float)W_) && (ix < 30);
    const float ccx = fminf(fmaxf(sx, 0.0f), (float)(W_ - 1));
    const float lox = floorf(ccx);
    const int   xl  = (int)lox;
    const int   xh  = min(xl + 1, W_ - 1);
    const float fx  = ccx - lox;
    const float vmx = vx_ ? 1.0f : 0.0f;
    const float wx0 = (1.0f - fx) * vmx;
    const float wx1 = fx * vmx;

    // --- span window (span <= 122 < 128 proven) ---
    const int s0    = __builtin_amdgcn_readfirstlane(xl);   // xl at ix=0
    const int s0c   = min(s0, W_ - 128);
    const int xh29  = __builtin_amdgcn_readlane(xh, 29);    // max needed col
    const int spanh = xh29 - s0c;
    const bool ldact = (ix * 4) <= spanh;                   // staging mask
    // invalid lanes (weight 0) read slot 0/128: staged every event, finite
    const int iA    = half * 128 + (vx_ ? (xl - s0c) : 0);

    const float* __restrict__ bpA = feat + ((size_t)b * C_ + c0) * (size_t)HW_;
    const float* __restrict__ gAl = bpA + (size_t)half * HW_ + s0c + 4 * ix;
    const float* __restrict__ gBl = gAl + 2 * HW_;

    const int  aw   = ix >> 1;
    const bool emit = ((lane & 1) == 0) && (aw < AW_);
    const int  iy0  = wave * 14;       // wave0: iy 0..15, wave1: iy 14..29

    // --- lane-parallel y-geometry: lane (lane&15) owns row iy0+l ---
    const int   l    = lane & 15;
    const float syl  = y1 + ((float)(iy0 + l) + 0.5f) * sub_h;
    const bool  vyl  = (syl > -1.0f) && (syl < (float)H_);
    const float ccyl = fminf(fmaxf(syl, 0.0f), (float)(H_ - 1));
    const float loyl = floorf(ccyl);
    const float fyl  = ccyl - loyl;
    const float vmyl = vyl ? 1.0f : 0.0f;
    const int   yll  = (int)loyl;
    const int   yhl  = min(yll + 1, H_ - 1);
    const int   wy0b = __float_as_int((1.0f - fyl) * vmyl);
    const int   wy1b = __float_as_int(fyl * vmyl);
    const int   olol = yll * W_;
    const int   ohil = yhl * W_;
    const int   pyll = __shfl_up(yll, 1, 64);   // prev row's yl (junk at l=0)
    const int   pyhl = __shfl_up(yhl, 1, 64);
    // case: 0 = reuse both rows, 1 = shift (yl == prev yh), 2 = stage both
    const int   casel = (l == 0) ? 2
                       : (yll == pyll) ? 0
                       : (yll == pyhl) ? 1 : 2;

    // --- prologue: stage row 0 (case forced 2) into buf0 ---
    {
        const int olo = __builtin_amdgcn_readlane(olol, 0);
        const int ohi = __builtin_amdgcn_readlane(ohil, 0);
        if (ldact) {
            GLOAD_LDS16(gAl + olo, LsW);
            GLOAD_LDS16(gBl + olo, LsW + 256);
            GLOAD_LDS16(gAl + ohi, LsW + 512);
            GLOAD_LDS16(gBl + ohi, LsW + 768);
        }
    }

    float alo0 = 0.f, alo1 = 0.f, ahi0 = 0.f, ahi1 = 0.f;
    float blo0 = 0.f, blo1 = 0.f, bhi0 = 0.f, bhi1 = 0.f;
    float outA[7], outB[7];
    float prevSA = 0.f, prevSB = 0.f, PA = 0.f, PB = 0.f;

    #pragma unroll
    for (int i = 0; i < 16; ++i) {
        // ---- issue row i+1's loads (case-dependent), counted vmcnt ----
        if (i < 15) {
            const int scn = __builtin_amdgcn_readlane(casel, i + 1);
            float* bn = LsW + ((i + 1) & 1) * 1024;
            if (scn == 2) {
                const int olo_n = __builtin_amdgcn_readlane(olol, i + 1);
                const int ohi_n = __builtin_amdgcn_readlane(ohil, i + 1);
                // guard: row i-1's ds_reads of bn must have executed
                asm volatile("s_waitcnt lgkmcnt(0)" ::: "memory");
                if (ldact) {
                    GLOAD_LDS16(gAl + olo_n, bn);
                    GLOAD_LDS16(gBl + olo_n, bn + 256);
                    GLOAD_LDS16(gAl + ohi_n, bn + 512);
                    GLOAD_LDS16(gBl + ohi_n, bn + 768);
                }
                // wait row i's loads; row i+1's 4 remain in flight
                asm volatile("s_waitcnt vmcnt(4)" ::: "memory");
            } else if (scn == 1) {
                const int ohi_n = __builtin_amdgcn_readlane(ohil, i + 1);
                asm volatile("s_waitcnt lgkmcnt(0)" ::: "memory");
                if (ldact) {
                    GLOAD_LDS16(gAl + ohi_n, bn + 512);
                    GLOAD_LDS16(gBl + ohi_n, bn + 768);
                }
                asm volatile("s_waitcnt vmcnt(2)" ::: "memory");
            } else {
                asm volatile("s_waitcnt vmcnt(0)" ::: "memory");
            }
        } else {
            asm volatile("s_waitcnt vmcnt(0)" ::: "memory");
        }

        // ---- consume row i from buf[i&1] ----
        const int   sci = __builtin_amdgcn_readlane(casel, i);
        const float wy0 = __int_as_float(__builtin_amdgcn_readlane(wy0b, i));
        const float wy1 = __int_as_float(__builtin_amdgcn_readlane(wy1b, i));
        const float* d  = LsW + (i & 1) * 1024;

        if (sci == 1) {
            alo0 = ahi0; alo1 = ahi1; blo0 = bhi0; blo1 = bhi1;
            ahi0 = d[512 + iA]; ahi1 = d[512 + iA + 1];
            bhi0 = d[768 + iA]; bhi1 = d[768 + iA + 1];
        } else if (sci == 2) {
            alo0 = d[iA];       alo1 = d[iA + 1];
            blo0 = d[256 + iA]; blo1 = d[256 + iA + 1];
            ahi0 = d[512 + iA]; ahi1 = d[512 + iA + 1];
            bhi0 = d[768 + iA]; bhi1 = d[768 + iA + 1];
        }
        // (sci == 0: registers already hold both rows)

        const float w00 = wy0 * wx0, w01 = wy0 * wx1;
        const float w10 = wy1 * wx0, w11 = wy1 * wx1;
        PA += alo0 * w00 + alo1 * w01 + ahi0 * w10 + ahi1 * w11;
        PB += blo0 * w00 + blo1 * w01 + bhi0 * w10 + bhi1 * w11;

        if (i & 1) {
            const float tA = PA + __shfl_xor(PA, 1, 64);
            const float uA = tA + __shfl_down(tA, 2, 64);
            const float tB = PB + __shfl_xor(PB, 1, 64);
            const float uB = tB + __shfl_down(tB, 2, 64);
            const int kk = i >> 1;
            if (kk > 0) {
                outA[kk - 1] = (prevSA + uA) * 0.0625f;
                outB[kk - 1] = (prevSB + uB) * 0.0625f;
            }
            prevSA = uA; prevSB = uB;
            PA = 0.f; PB = 0.f;
        }
    }

    // --- overlay out staging on the (dead) row buffers, write coalesced ---
    if (emit) {
        #pragma unroll
        for (int k = 0; k < 7; ++k) {
            LsW[half * 98 + k * AW_ + aw]       = outA[k];
            LsW[(2 + half) * 98 + k * AW_ + aw] = outB[k];
        }
    }
    float* __restrict__ op = out + ((size_t)n * C_ + c0) * (AH_ * AW_);
    for (int o = lane; o < CPB * 7 * AW_; o += 64) {   // 392 floats
        const int ch  = o / 98;
        const int rem = o - ch * 98;
        op[ch * (AH_ * AW_) + wave * 98 + rem] = LsW[o];
    }
}

extern "C" void kernel_launch(void* const* d_in, const int* in_sizes, int n_in,
                              void* d_out, int out_size, void* d_ws, size_t ws_size,
                              hipStream_t stream) {
    const float* feat = (const float*)d_in[0];
    const float* rois = (const float*)d_in[1];
    float* out = (float*)d_out;
    const int grid = 256 * (C_ / CPB);   // 16384 blocks, 128 threads
    roi_mask_align_avg_kernel<<<grid, 128, 0, stream>>>(feat, rois, out);
}